// Round 1
// baseline (5910.422 us; speedup 1.0000x reference)
//
#include <hip/hip_runtime.h>
#include <hip/hip_fp16.h>

// Problem constants
constexpr int BN_  = 16;                 // batch
constexpr int SN_  = 577;                // seq
constexpr int DN_  = 768;                // model dim
constexpr int HN_  = 12;                 // heads
constexpr int HD_  = 64;                 // head dim
constexpr int NB_  = 50;                 // rpe buckets
constexpr int MR_  = BN_ * SN_;          // 9232 rows of x
constexpr int BHS_ = BN_ * HN_ * SN_;    // 110784 (b,h,i) rows
constexpr int SHD_ = SN_ * HD_;          // 36928

// ---------------------------------------------------------------------------
// Kernel 1: qkv = x @ w^T  (f32, 128x128x8 tiles, 8x8 per thread)
// Epilogue scatters into dense Q/K/V[b][h][i][d] buffers, honoring the
// torch-faithful flat reshape (s*768+col) -> (h*577+i)*64+d, Q scaled 1/8.
// ---------------------------------------------------------------------------
__launch_bounds__(256, 2)
__global__ void qkv_gemm_k(const float* __restrict__ x, const float* __restrict__ w,
                           float* __restrict__ Qb, float* __restrict__ Kb,
                           float* __restrict__ Vb) {
  __shared__ float As[8][132];
  __shared__ float Bs[8][132];
  const int t = threadIdx.x;
  const int tx = t & 15, ty = t >> 4;
  const int m0 = blockIdx.y * 128, n0 = blockIdx.x * 128;
  const int lrow = t >> 1, lk = (t & 1) * 4;

  float acc[8][8];
#pragma unroll
  for (int i = 0; i < 8; ++i)
#pragma unroll
    for (int j = 0; j < 8; ++j) acc[i][j] = 0.f;

  const int gm = m0 + lrow;
  const bool mok = gm < MR_;
  const float* ap = x + (size_t)(mok ? gm : MR_ - 1) * DN_ + lk;
  const float* bp = w + (size_t)(n0 + lrow) * DN_ + lk;

  for (int k0 = 0; k0 < DN_; k0 += 8) {
    const float4 av = *(const float4*)(ap + k0);
    const float4 bv = *(const float4*)(bp + k0);
    __syncthreads();
    As[lk + 0][lrow] = av.x; As[lk + 1][lrow] = av.y;
    As[lk + 2][lrow] = av.z; As[lk + 3][lrow] = av.w;
    Bs[lk + 0][lrow] = bv.x; Bs[lk + 1][lrow] = bv.y;
    Bs[lk + 2][lrow] = bv.z; Bs[lk + 3][lrow] = bv.w;
    __syncthreads();
#pragma unroll
    for (int kk = 0; kk < 8; ++kk) {
      const float4 a0 = *(const float4*)&As[kk][ty * 4];
      const float4 a1 = *(const float4*)&As[kk][64 + ty * 4];
      const float4 b0 = *(const float4*)&Bs[kk][tx * 4];
      const float4 b1 = *(const float4*)&Bs[kk][64 + tx * 4];
      const float ar[8] = {a0.x, a0.y, a0.z, a0.w, a1.x, a1.y, a1.z, a1.w};
      const float br[8] = {b0.x, b0.y, b0.z, b0.w, b1.x, b1.y, b1.z, b1.w};
#pragma unroll
      for (int i = 0; i < 8; ++i)
#pragma unroll
        for (int j = 0; j < 8; ++j) acc[i][j] += ar[i] * br[j];
    }
  }

#pragma unroll
  for (int i = 0; i < 8; ++i) {
    const int gmr = m0 + (i < 4 ? ty * 4 + i : 64 + ty * 4 + (i - 4));
    if (gmr >= MR_) continue;
    const int bb = gmr / SN_;
    const int ss = gmr - bb * SN_;
#pragma unroll
    for (int jq = 0; jq < 2; ++jq) {
      const int gn  = n0 + jq * 64 + tx * 4;   // sec uniform within 64-span
      const int sec = gn / DN_;
      const int col = gn - sec * DN_;
      const int p   = ss * DN_ + col;
      const int hh  = p / SHD_;
      const int rem = p - hh * SHD_;
      const int ii  = rem >> 6;
      const int dd  = rem & 63;
      float4 v = make_float4(acc[i][jq * 4 + 0], acc[i][jq * 4 + 1],
                             acc[i][jq * 4 + 2], acc[i][jq * 4 + 3]);
      if (sec == 0) { v.x *= 0.125f; v.y *= 0.125f; v.z *= 0.125f; v.w *= 0.125f; }
      float* dst = (sec == 0) ? Qb : (sec == 1 ? Kb : Vb);
      *(float4*)(dst + (((size_t)(bb * HN_ + hh) * SN_ + ii) << 6) + dd) = v;
    }
  }
}

// ---------------------------------------------------------------------------
// Kernel 2: ctx[m][c] = Q_row(m) . rpe_table[:, c]   (m = flat (b,h,i) row)
// ---------------------------------------------------------------------------
__launch_bounds__(256, 2)
__global__ void ctx_k(const float* __restrict__ Qb, const float* __restrict__ rpe,
                      float* __restrict__ ctxg) {
  __shared__ float Qt[64][68];
  __shared__ float Rt[NB_][68];   // transposed rpe: [c][d]
  const int t = threadIdx.x;
  const int m0 = blockIdx.x * 64;
  {
    const int r = t >> 2, d0 = (t & 3) * 16;
    int gm = m0 + r; if (gm >= BHS_) gm = BHS_ - 1;
    const float* qp = Qb + ((size_t)gm << 6) + d0;
#pragma unroll
    for (int e = 0; e < 4; ++e)
      *(float4*)&Qt[r][d0 + e * 4] = *(const float4*)(qp + e * 4);
  }
  for (int e = t; e < HD_ * NB_; e += 256) {
    const int d = e / NB_, c = e - d * NB_;
    Rt[c][d] = rpe[e];
  }
  __syncthreads();
  const int ti = t >> 4, tj = t & 15;
  float acc[4][4];
#pragma unroll
  for (int rr = 0; rr < 4; ++rr)
#pragma unroll
    for (int cc = 0; cc < 4; ++cc) acc[rr][cc] = 0.f;
#pragma unroll
  for (int d4 = 0; d4 < 16; ++d4) {
    float4 q[4], rv[4];
#pragma unroll
    for (int rr = 0; rr < 4; ++rr)
      q[rr] = *(const float4*)&Qt[ti + 16 * rr][d4 * 4];
#pragma unroll
    for (int cc = 0; cc < 4; ++cc) {
      int c = tj + 16 * cc; if (c >= NB_) c = NB_ - 1;
      rv[cc] = *(const float4*)&Rt[c][d4 * 4];
    }
#pragma unroll
    for (int rr = 0; rr < 4; ++rr)
#pragma unroll
      for (int cc = 0; cc < 4; ++cc)
        acc[rr][cc] += q[rr].x * rv[cc].x + q[rr].y * rv[cc].y +
                       q[rr].z * rv[cc].z + q[rr].w * rv[cc].w;
  }
#pragma unroll
  for (int rr = 0; rr < 4; ++rr) {
    const int gm = m0 + ti + 16 * rr;
    if (gm >= BHS_) continue;
#pragma unroll
    for (int cc = 0; cc < 4; ++cc) {
      const int c = tj + 16 * cc;
      if (c < NB_) ctxg[(size_t)gm * NB_ + c] = acc[rr][cc];
    }
  }
}

// ---------------------------------------------------------------------------
// Kernel 3: flash attention with iRPE contextual bias.
// One block per (bh, 64-row q-tile); K-tiles of 64; 4i x 4j per thread
// (strided assignments for conflict-free b128 LDS reads); online softmax;
// K and V time-share one LDS buffer (static LDS must stay < 64 KB).
// ---------------------------------------------------------------------------
__launch_bounds__(256, 2)
__global__ void attn_k(const float* __restrict__ Qb, const float* __restrict__ Kb,
                       const float* __restrict__ Vb, const float* __restrict__ ctxg,
                       const int* __restrict__ rpb, float* __restrict__ y) {
  __shared__ float  Qs[64][68];
  __shared__ float  KVs[64][68];
  __shared__ __half Ps[64][66];
  __shared__ float  ctxs[64][NB_];
  __shared__ float  mrow[64], lrow[64], srow[64];

  const int t  = threadIdx.x;
  const int qt = blockIdx.x, bh = blockIdx.y;
  const int b  = bh / HN_, h = bh - b * HN_;
  const int i0 = qt * 64;
  const size_t rowbase = (size_t)bh * SN_;

  {  // load Q tile (already scaled by 1/8 in GEMM epilogue)
    const int r = t >> 2, d0 = (t & 3) * 16;
    int gi = i0 + r; if (gi >= SN_) gi = SN_ - 1;
    const float* qp = Qb + ((rowbase + gi) << 6) + d0;
#pragma unroll
    for (int e = 0; e < 4; ++e)
      *(float4*)&Qs[r][d0 + e * 4] = *(const float4*)(qp + e * 4);
  }
  for (int e = t; e < 64 * NB_; e += 256) {  // load ctx tile
    const int i = e / NB_, c = e - i * NB_;
    int gi = i0 + i; if (gi >= SN_) gi = SN_ - 1;
    ctxs[i][c] = ctxg[(rowbase + gi) * NB_ + c];
  }
  if (t < 64) { mrow[t] = -3e38f; lrow[t] = 0.f; srow[t] = 0.f; }

  float acc[16];
#pragma unroll
  for (int e = 0; e < 16; ++e) acc[e] = 0.f;

  const int ti = t >> 4, tj = t & 15;     // logits: rows ti+16rr, cols tj+16cc
  const int rp = t >> 3, dpv = (t & 7) * 8;  // PV: rows rp, rp+32; d-slice dpv

  __syncthreads();

  for (int jt = 0; jt < 10; ++jt) {
    const int j0 = jt * 64;
    {  // stage K
      const int r = t >> 2, d0 = (t & 3) * 16;
      int gj = j0 + r; if (gj >= SN_) gj = SN_ - 1;
      const float* kp = Kb + ((rowbase + gj) << 6) + d0;
#pragma unroll
      for (int e = 0; e < 4; ++e)
        *(float4*)&KVs[r][d0 + e * 4] = *(const float4*)(kp + e * 4);
    }
    __syncthreads();

    // logits (Q.K)
    float lg[4][4];
#pragma unroll
    for (int rr = 0; rr < 4; ++rr)
#pragma unroll
      for (int cc = 0; cc < 4; ++cc) lg[rr][cc] = 0.f;
#pragma unroll
    for (int d4 = 0; d4 < 16; ++d4) {
      float4 q[4], kf[4];
#pragma unroll
      for (int rr = 0; rr < 4; ++rr)
        q[rr] = *(const float4*)&Qs[ti + 16 * rr][d4 * 4];
#pragma unroll
      for (int cc = 0; cc < 4; ++cc)
        kf[cc] = *(const float4*)&KVs[tj + 16 * cc][d4 * 4];
#pragma unroll
      for (int rr = 0; rr < 4; ++rr)
#pragma unroll
        for (int cc = 0; cc < 4; ++cc)
          lg[rr][cc] += q[rr].x * kf[cc].x + q[rr].y * kf[cc].y +
                        q[rr].z * kf[cc].z + q[rr].w * kf[cc].w;
    }
    // + contextual rpe bias, mask j >= S
#pragma unroll
    for (int rr = 0; rr < 4; ++rr) {
      const int gi = i0 + ti + 16 * rr;
      const int gir = gi < SN_ ? gi : SN_ - 1;
#pragma unroll
      for (int cc = 0; cc < 4; ++cc) {
        const int gj = j0 + tj + 16 * cc;
        if (gj < SN_) {
          const int bkt = rpb[gir * SN_ + gj];
          lg[rr][cc] += ctxs[ti + 16 * rr][bkt];
        } else {
          lg[rr][cc] = -3e38f;
        }
      }
    }
    // online softmax (rows live in one 16-lane group -> shfl butterflies)
#pragma unroll
    for (int rr = 0; rr < 4; ++rr) {
      const int r = ti + 16 * rr;
      float mx = fmaxf(fmaxf(lg[rr][0], lg[rr][1]), fmaxf(lg[rr][2], lg[rr][3]));
#pragma unroll
      for (int msk = 8; msk >= 1; msk >>= 1) mx = fmaxf(mx, __shfl_xor(mx, msk));
      const float mold = mrow[r];
      const float mnew = fmaxf(mold, mx);
      const float p0 = __expf(lg[rr][0] - mnew);
      const float p1 = __expf(lg[rr][1] - mnew);
      const float p2 = __expf(lg[rr][2] - mnew);
      const float p3 = __expf(lg[rr][3] - mnew);
      float sm = (p0 + p1) + (p2 + p3);
#pragma unroll
      for (int msk = 8; msk >= 1; msk >>= 1) sm += __shfl_xor(sm, msk);
      Ps[r][tj]      = __float2half(p0);
      Ps[r][tj + 16] = __float2half(p1);
      Ps[r][tj + 32] = __float2half(p2);
      Ps[r][tj + 48] = __float2half(p3);
      if (tj == 0) {
        const float sc = __expf(mold - mnew);
        srow[r] = sc;
        lrow[r] = lrow[r] * sc + sm;
        mrow[r] = mnew;
      }
    }
    __syncthreads();
    {  // stage V (reuses K buffer; all K reads done)
      const int r = t >> 2, d0 = (t & 3) * 16;
      int gj = j0 + r; if (gj >= SN_) gj = SN_ - 1;
      const float* vp = Vb + ((rowbase + gj) << 6) + d0;
#pragma unroll
      for (int e = 0; e < 4; ++e)
        *(float4*)&KVs[r][d0 + e * 4] = *(const float4*)(vp + e * 4);
    }
    __syncthreads();
    {  // PV accumulate
      const float sc0 = srow[rp], sc1 = srow[rp + 32];
#pragma unroll
      for (int e = 0; e < 8; ++e)  acc[e] *= sc0;
#pragma unroll
      for (int e = 8; e < 16; ++e) acc[e] *= sc1;
#pragma unroll 8
      for (int j = 0; j < 64; ++j) {
        const float p0 = __half2float(Ps[rp][j]);
        const float p1 = __half2float(Ps[rp + 32][j]);
        const float4 v0 = *(const float4*)&KVs[j][dpv];
        const float4 v1 = *(const float4*)&KVs[j][dpv + 4];
        acc[0]  += p0 * v0.x; acc[1]  += p0 * v0.y;
        acc[2]  += p0 * v0.z; acc[3]  += p0 * v0.w;
        acc[4]  += p0 * v1.x; acc[5]  += p0 * v1.y;
        acc[6]  += p0 * v1.z; acc[7]  += p0 * v1.w;
        acc[8]  += p1 * v0.x; acc[9]  += p1 * v0.y;
        acc[10] += p1 * v0.z; acc[11] += p1 * v0.w;
        acc[12] += p1 * v1.x; acc[13] += p1 * v1.y;
        acc[14] += p1 * v1.z; acc[15] += p1 * v1.w;
      }
    }
    __syncthreads();
  }

  // write y[b, i, h*64+d] = acc / l
  {
    const int gi0 = i0 + rp;
    if (gi0 < SN_) {
      const float inv = 1.f / lrow[rp];
      float* yp = y + ((size_t)b * SN_ + gi0) * DN_ + h * HD_ + dpv;
      *(float4*)yp       = make_float4(acc[0] * inv, acc[1] * inv, acc[2] * inv, acc[3] * inv);
      *(float4*)(yp + 4) = make_float4(acc[4] * inv, acc[5] * inv, acc[6] * inv, acc[7] * inv);
    }
    const int gi1 = i0 + rp + 32;
    if (gi1 < SN_) {
      const float inv = 1.f / lrow[rp + 32];
      float* yp = y + ((size_t)b * SN_ + gi1) * DN_ + h * HD_ + dpv;
      *(float4*)yp       = make_float4(acc[8] * inv, acc[9] * inv, acc[10] * inv, acc[11] * inv);
      *(float4*)(yp + 4) = make_float4(acc[12] * inv, acc[13] * inv, acc[14] * inv, acc[15] * inv);
    }
  }
}

// ---------------------------------------------------------------------------
extern "C" void kernel_launch(void* const* d_in, const int* in_sizes, int n_in,
                              void* d_out, int out_size, void* d_ws, size_t ws_size,
                              hipStream_t stream) {
  const float* x   = (const float*)d_in[0];
  const float* w   = (const float*)d_in[1];
  const float* rpe = (const float*)d_in[2];
  const int*   rpb = (const int*)d_in[3];
  float* y = (float*)d_out;

  float* Qb   = (float*)d_ws;                       // 28.4 MB
  float* Kb   = Qb + (size_t)BHS_ * HD_;            // 28.4 MB
  float* Vb   = Kb + (size_t)BHS_ * HD_;            // 28.4 MB
  float* ctxg = Vb + (size_t)BHS_ * HD_;            // 22.2 MB

  qkv_gemm_k<<<dim3(18, 73), 256, 0, stream>>>(x, w, Qb, Kb, Vb);
  ctx_k<<<dim3((BHS_ + 63) / 64), 256, 0, stream>>>(Qb, rpe, ctxg);
  attn_k<<<dim3(10, 192), 256, 0, stream>>>(Qb, Kb, Vb, ctxg, rpb, y);
}

// Round 2
// 944.281 us; speedup vs baseline: 6.2592x; 6.2592x over previous
//
#include <hip/hip_runtime.h>
#include <hip/hip_fp16.h>

// Problem constants
constexpr int BN_  = 16;                 // batch
constexpr int SN_  = 577;                // seq
constexpr int SP_  = 640;                // padded seq (multiple of 64)
constexpr int DN_  = 768;                // model dim
constexpr int HN_  = 12;                 // heads
constexpr int HD_  = 64;                 // head dim
constexpr int NB_  = 50;                 // rpe buckets
constexpr int MR_  = BN_ * SN_;          // 9232 rows of x
constexpr int BHS_ = BN_ * HN_ * SN_;    // 110784 (b,h,i) rows
constexpr int SHD_ = SN_ * HD_;          // 36928

typedef __attribute__((ext_vector_type(8))) short short8;
typedef __attribute__((ext_vector_type(4))) float f32x4;

__device__ __forceinline__ short f2bf(float f) {
  union { float f; unsigned u; } v; v.f = f;
  unsigned r = (v.u + 0x7fffu + ((v.u >> 16) & 1u)) >> 16;
  return (short)r;
}

// ---------------------------------------------------------------------------
// Kernel 1: qkv = x @ w^T  (f32, 128x128x8 tiles, 8x8 per thread)
// Epilogue: Q -> f32 (scaled 1/8); K -> bf16, swizzled (short idx ^ (j&7)<<3);
// V -> bf16 row-major (transposed+swizzled later by vtr_k).
// ---------------------------------------------------------------------------
__launch_bounds__(256, 2)
__global__ void qkv_gemm_k(const float* __restrict__ x, const float* __restrict__ w,
                           float* __restrict__ Qb, short* __restrict__ Ksw,
                           short* __restrict__ Vbf) {
  __shared__ float As[8][132];
  __shared__ float Bs[8][132];
  const int t = threadIdx.x;
  const int tx = t & 15, ty = t >> 4;
  const int m0 = blockIdx.y * 128, n0 = blockIdx.x * 128;
  const int lrow = t >> 1, lk = (t & 1) * 4;

  float acc[8][8];
#pragma unroll
  for (int i = 0; i < 8; ++i)
#pragma unroll
    for (int j = 0; j < 8; ++j) acc[i][j] = 0.f;

  const int gm = m0 + lrow;
  const bool mok = gm < MR_;
  const float* ap = x + (size_t)(mok ? gm : MR_ - 1) * DN_ + lk;
  const float* bp = w + (size_t)(n0 + lrow) * DN_ + lk;

  for (int k0 = 0; k0 < DN_; k0 += 8) {
    const float4 av = *(const float4*)(ap + k0);
    const float4 bv = *(const float4*)(bp + k0);
    __syncthreads();
    As[lk + 0][lrow] = av.x; As[lk + 1][lrow] = av.y;
    As[lk + 2][lrow] = av.z; As[lk + 3][lrow] = av.w;
    Bs[lk + 0][lrow] = bv.x; Bs[lk + 1][lrow] = bv.y;
    Bs[lk + 2][lrow] = bv.z; Bs[lk + 3][lrow] = bv.w;
    __syncthreads();
#pragma unroll
    for (int kk = 0; kk < 8; ++kk) {
      const float4 a0 = *(const float4*)&As[kk][ty * 4];
      const float4 a1 = *(const float4*)&As[kk][64 + ty * 4];
      const float4 b0 = *(const float4*)&Bs[kk][tx * 4];
      const float4 b1 = *(const float4*)&Bs[kk][64 + tx * 4];
      const float ar[8] = {a0.x, a0.y, a0.z, a0.w, a1.x, a1.y, a1.z, a1.w};
      const float br[8] = {b0.x, b0.y, b0.z, b0.w, b1.x, b1.y, b1.z, b1.w};
#pragma unroll
      for (int i = 0; i < 8; ++i)
#pragma unroll
        for (int j = 0; j < 8; ++j) acc[i][j] += ar[i] * br[j];
    }
  }

#pragma unroll
  for (int i = 0; i < 8; ++i) {
    const int gmr = m0 + (i < 4 ? ty * 4 + i : 64 + ty * 4 + (i - 4));
    if (gmr >= MR_) continue;
    const int bb = gmr / SN_;
    const int ss = gmr - bb * SN_;
#pragma unroll
    for (int jq = 0; jq < 2; ++jq) {
      const int gn  = n0 + jq * 64 + tx * 4;   // sec uniform within 64-span
      const int sec = gn / DN_;
      const int col = gn - sec * DN_;
      const int p   = ss * DN_ + col;
      const int hh  = p / SHD_;
      const int rem = p - hh * SHD_;
      const int ii  = rem >> 6;
      const int dd  = rem & 63;
      const float4 v = make_float4(acc[i][jq * 4 + 0], acc[i][jq * 4 + 1],
                                   acc[i][jq * 4 + 2], acc[i][jq * 4 + 3]);
      const size_t rowidx = (size_t)(bb * HN_ + hh);
      if (sec == 0) {
        float4 q = make_float4(v.x * 0.125f, v.y * 0.125f, v.z * 0.125f, v.w * 0.125f);
        *(float4*)(Qb + ((rowidx * SN_ + ii) << 6) + dd) = q;
      } else {
        short4 s;
        s.x = f2bf(v.x); s.y = f2bf(v.y); s.z = f2bf(v.z); s.w = f2bf(v.w);
        if (sec == 1) {
          *(short4*)(Ksw + (rowidx * SP_ + ii) * 64 + (dd ^ ((ii & 7) << 3))) = s;
        } else {
          *(short4*)(Vbf + (rowidx * SP_ + ii) * 64 + dd) = s;
        }
      }
    }
  }
}

// ---------------------------------------------------------------------------
// Kernel 2: transpose V per (bh): Vbf[j][d] -> Vtsw[d][j], bf16, swizzled
// (short col index ^ ((d&7)<<3)); pad cols j>=577 zeroed.
// ---------------------------------------------------------------------------
__launch_bounds__(256)
__global__ void vtr_k(const short* __restrict__ Vbf, short* __restrict__ Vtsw) {
  __shared__ short T[64][72];
  const int t = threadIdx.x;
  const int jt = blockIdx.x, bh = blockIdx.y;
  const int j0 = jt * 64;
  {
    const int r = t >> 2, c0 = (t & 3) * 16;
    const short* src = Vbf + ((size_t)bh * SP_ + j0 + r) * 64 + c0;
    *(short8*)&T[r][c0]     = *(const short8*)(src);
    *(short8*)&T[r][c0 + 8] = *(const short8*)(src + 8);
  }
  __syncthreads();
  const int d = t >> 2;
  short* dst = Vtsw + ((size_t)bh * 64 + d) * SP_;
  const int sw = (d & 7) << 3;
#pragma unroll
  for (int e = 0; e < 4; ++e) {
    const int jl = (t & 3) * 16 + e * 4;
    const int jg = j0 + jl;
    short4 v;
    v.x = (jg + 0 < SN_) ? T[jl + 0][d] : (short)0;
    v.y = (jg + 1 < SN_) ? T[jl + 1][d] : (short)0;
    v.z = (jg + 2 < SN_) ? T[jl + 2][d] : (short)0;
    v.w = (jg + 3 < SN_) ? T[jl + 3][d] : (short)0;
    *(short4*)&dst[jg ^ sw] = v;
  }
}

// ---------------------------------------------------------------------------
// Kernel 3: ctx[m][c] = Q_row(m) . rpe_table[:, c]  (f32, unchanged)
// ---------------------------------------------------------------------------
__launch_bounds__(256, 2)
__global__ void ctx_k(const float* __restrict__ Qb, const float* __restrict__ rpe,
                      float* __restrict__ ctxg) {
  __shared__ float Qt[64][68];
  __shared__ float Rt[NB_][68];
  const int t = threadIdx.x;
  const int m0 = blockIdx.x * 64;
  {
    const int r = t >> 2, d0 = (t & 3) * 16;
    int gm = m0 + r; if (gm >= BHS_) gm = BHS_ - 1;
    const float* qp = Qb + ((size_t)gm << 6) + d0;
#pragma unroll
    for (int e = 0; e < 4; ++e)
      *(float4*)&Qt[r][d0 + e * 4] = *(const float4*)(qp + e * 4);
  }
  for (int e = t; e < HD_ * NB_; e += 256) {
    const int d = e / NB_, c = e - d * NB_;
    Rt[c][d] = rpe[e];
  }
  __syncthreads();
  const int ti = t >> 4, tj = t & 15;
  float acc[4][4];
#pragma unroll
  for (int rr = 0; rr < 4; ++rr)
#pragma unroll
    for (int cc = 0; cc < 4; ++cc) acc[rr][cc] = 0.f;
#pragma unroll
  for (int d4 = 0; d4 < 16; ++d4) {
    float4 q[4], rv[4];
#pragma unroll
    for (int rr = 0; rr < 4; ++rr)
      q[rr] = *(const float4*)&Qt[ti + 16 * rr][d4 * 4];
#pragma unroll
    for (int cc = 0; cc < 4; ++cc) {
      int c = tj + 16 * cc; if (c >= NB_) c = NB_ - 1;
      rv[cc] = *(const float4*)&Rt[c][d4 * 4];
    }
#pragma unroll
    for (int rr = 0; rr < 4; ++rr)
#pragma unroll
      for (int cc = 0; cc < 4; ++cc)
        acc[rr][cc] += q[rr].x * rv[cc].x + q[rr].y * rv[cc].y +
                       q[rr].z * rv[cc].z + q[rr].w * rv[cc].w;
  }
#pragma unroll
  for (int rr = 0; rr < 4; ++rr) {
    const int gm = m0 + ti + 16 * rr;
    if (gm >= BHS_) continue;
#pragma unroll
    for (int cc = 0; cc < 4; ++cc) {
      const int c = tj + 16 * cc;
      if (c < NB_) ctxg[(size_t)gm * NB_ + c] = acc[rr][cc];
    }
  }
}

// ---------------------------------------------------------------------------
// Kernel 4: MFMA flash attention with iRPE contextual bias.
// Block = (bh, 64-row q-tile), 4 waves x 16 q-rows. 16x16x32 bf16 MFMA.
// K tile [j][d], V^T tile [d][j] in LDS, both XOR-swizzled ((row&7)<<4 bytes)
// so b128 fragment reads are ~2-way. P via per-wave LDS (bf16).
// A/B fragment k-slot maps are chosen identically (k = kc*32 + 8g + jj) so the
// MFMA dot product is correct for any hardware slot->k bijection.
// ---------------------------------------------------------------------------
__launch_bounds__(256)
__global__ void attn_k(const float* __restrict__ Qb, const short* __restrict__ Ksw,
                       const short* __restrict__ Vtsw, const float* __restrict__ ctxg,
                       const int* __restrict__ rpb, float* __restrict__ y) {
  __shared__ short Kt[64 * 64];        // 8 KB
  __shared__ short Vt[64 * 64];        // 8 KB
  __shared__ short Pt[4][16 * 64];     // 8 KB (per-wave P tiles)
  __shared__ float ctxs[64][52];       // 13.3 KB

  const int t = threadIdx.x;
  const int w = t >> 6, lane = t & 63, g = lane >> 4, ln = lane & 15;
  const int qt = blockIdx.x, bh = blockIdx.y;
  const int b = bh / HN_, h = bh - b * HN_;
  const int i0 = qt * 64;
  const size_t rb = (size_t)bh * SN_;
  const short* Kbh = Ksw + (size_t)bh * SP_ * 64;
  const short* Vbh = Vtsw + (size_t)bh * 64 * SP_;

  // stage ctx tile (f32)
  for (int e = t; e < 64 * NB_; e += 256) {
    const int i = e / NB_, c = e - i * NB_;
    int gi = i0 + i; if (gi > SN_ - 1) gi = SN_ - 1;
    ctxs[i][c] = ctxg[(rb + gi) * NB_ + c];
  }

  // Q fragments (row m = ln of this wave's 16-row band), bf16
  short8 qf[2];
  {
    int row = i0 + 16 * w + ln; if (row > SN_ - 1) row = SN_ - 1;
    const float* qp = Qb + ((rb + row) << 6);
#pragma unroll
    for (int kc = 0; kc < 2; ++kc) {
      const float4 a = *(const float4*)(qp + kc * 32 + 8 * g);
      const float4 c = *(const float4*)(qp + kc * 32 + 8 * g + 4);
      union { short8 v; short u[8]; } pk;
      pk.u[0] = f2bf(a.x); pk.u[1] = f2bf(a.y); pk.u[2] = f2bf(a.z); pk.u[3] = f2bf(a.w);
      pk.u[4] = f2bf(c.x); pk.u[5] = f2bf(c.y); pk.u[6] = f2bf(c.z); pk.u[7] = f2bf(c.w);
      qf[kc] = pk.v;
    }
  }

  float mrow[4], lrow[4];
#pragma unroll
  for (int r = 0; r < 4; ++r) { mrow[r] = -3e38f; lrow[r] = 0.f; }
  f32x4 accO[4];
#pragma unroll
  for (int dt = 0; dt < 4; ++dt) accO[dt] = (f32x4){0.f, 0.f, 0.f, 0.f};

  __syncthreads();

  for (int jt = 0; jt < 10; ++jt) {
    const int j0 = jt * 64;
    {  // stage K tile + V^T tile (issue loads early, write after barrier)
      const int r = t >> 2, c0 = (t & 3) * 16;
      const short* ks = Kbh + (size_t)(j0 + r) * 64 + c0;
      const short8 k0 = *(const short8*)(ks);
      const short8 k1 = *(const short8*)(ks + 8);
      const short* vs = Vbh + (size_t)r * SP_ + j0 + c0;
      const short8 v0 = *(const short8*)(vs);
      const short8 v1 = *(const short8*)(vs + 8);
      __syncthreads();  // prior step's LDS reads complete
      *(short8*)&Kt[r * 64 + c0]     = k0;
      *(short8*)&Kt[r * 64 + c0 + 8] = k1;
      *(short8*)&Vt[r * 64 + c0]     = v0;
      *(short8*)&Vt[r * 64 + c0 + 8] = v1;
      __syncthreads();
    }

    // QK^T: S tile 16 x 64 per wave
    f32x4 accS[4];
#pragma unroll
    for (int nt = 0; nt < 4; ++nt) accS[nt] = (f32x4){0.f, 0.f, 0.f, 0.f};
#pragma unroll
    for (int kc = 0; kc < 2; ++kc) {
      const int cb = (kc * 32 + 8 * g) ^ ((ln & 7) << 3);
#pragma unroll
      for (int nt = 0; nt < 4; ++nt) {
        const short8 kf = *(const short8*)&Kt[(nt * 16 + ln) * 64 + cb];
        accS[nt] = __builtin_amdgcn_mfma_f32_16x16x32_bf16(qf[kc], kf, accS[nt], 0, 0, 0);
      }
    }

    // bias + mask
    float pv[4][4];
#pragma unroll
    for (int nt = 0; nt < 4; ++nt) {
      const int jg = j0 + nt * 16 + ln;
#pragma unroll
      for (int r = 0; r < 4; ++r) {
        float sv = accS[nt][r];
        if (jg < SN_) {
          const int il = 16 * w + 4 * g + r;
          int irow = i0 + il; if (irow > SN_ - 1) irow = SN_ - 1;
          sv += ctxs[il][rpb[irow * SN_ + jg]];
        } else {
          sv = -3e38f;
        }
        pv[nt][r] = sv;
      }
    }

    // online softmax (row = 4g+r lives in one 16-lane group)
#pragma unroll
    for (int r = 0; r < 4; ++r) {
      float mx = fmaxf(fmaxf(pv[0][r], pv[1][r]), fmaxf(pv[2][r], pv[3][r]));
#pragma unroll
      for (int msk = 8; msk >= 1; msk >>= 1) mx = fmaxf(mx, __shfl_xor(mx, msk));
      const float mnew = fmaxf(mrow[r], mx);
      const float sc = __expf(mrow[r] - mnew);
      mrow[r] = mnew;
      float sum = 0.f;
#pragma unroll
      for (int nt = 0; nt < 4; ++nt) {
        pv[nt][r] = __expf(pv[nt][r] - mnew);
        sum += pv[nt][r];
      }
#pragma unroll
      for (int msk = 8; msk >= 1; msk >>= 1) sum += __shfl_xor(sum, msk);
      lrow[r] = lrow[r] * sc + sum;
#pragma unroll
      for (int dt = 0; dt < 4; ++dt) accO[dt][r] *= sc;
      const int il = 4 * g + r;
      const int swp = (il & 7) << 3;
#pragma unroll
      for (int nt = 0; nt < 4; ++nt)
        Pt[w][il * 64 + ((nt * 16 + ln) ^ swp)] = f2bf(pv[nt][r]);
    }

    // PV: O += P . V   (P per-wave in LDS; no barrier needed, same-wave RAW)
#pragma unroll
    for (int kc = 0; kc < 2; ++kc) {
      const int cb = (kc * 32 + 8 * g) ^ ((ln & 7) << 3);
      const short8 pf = *(const short8*)&Pt[w][ln * 64 + cb];
#pragma unroll
      for (int dt = 0; dt < 4; ++dt) {
        const short8 vf = *(const short8*)&Vt[(dt * 16 + ln) * 64 + cb];
        accO[dt] = __builtin_amdgcn_mfma_f32_16x16x32_bf16(pf, vf, accO[dt], 0, 0, 0);
      }
    }
  }

  // epilogue: y[b, i, h*64 + d] = O / l
#pragma unroll
  for (int r = 0; r < 4; ++r) {
    const int i = i0 + 16 * w + 4 * g + r;
    if (i >= SN_) continue;
    const float inv = 1.f / lrow[r];
    float* yp = y + ((size_t)b * SN_ + i) * DN_ + h * HD_ + ln;
#pragma unroll
    for (int dt = 0; dt < 4; ++dt) yp[dt * 16] = accO[dt][r] * inv;
  }
}

// ---------------------------------------------------------------------------
extern "C" void kernel_launch(void* const* d_in, const int* in_sizes, int n_in,
                              void* d_out, int out_size, void* d_ws, size_t ws_size,
                              hipStream_t stream) {
  const float* x   = (const float*)d_in[0];
  const float* w   = (const float*)d_in[1];
  const float* rpe = (const float*)d_in[2];
  const int*   rpb = (const int*)d_in[3];
  float* y = (float*)d_out;

  float* Qb   = (float*)d_ws;                               // 28.4 MB f32
  short* Ksw  = (short*)(Qb + (size_t)BHS_ * HD_);          // 15.7 MB bf16 swizzled
  short* Vbf  = Ksw + (size_t)BN_ * HN_ * SP_ * 64;         // 15.7 MB bf16
  short* Vtsw = Vbf + (size_t)BN_ * HN_ * SP_ * 64;         // 15.7 MB bf16 swizzled
  float* ctxg = (float*)(Vtsw + (size_t)BN_ * HN_ * 64 * SP_);  // 22.2 MB f32

  qkv_gemm_k<<<dim3(18, 73), 256, 0, stream>>>(x, w, Qb, Ksw, Vbf);
  vtr_k<<<dim3(10, BN_ * HN_), 256, 0, stream>>>(Vbf, Vtsw);
  ctx_k<<<dim3((BHS_ + 63) / 64), 256, 0, stream>>>(Qb, rpe, ctxg);
  attn_k<<<dim3(10, BN_ * HN_), 256, 0, stream>>>(Qb, Ksw, Vtsw, ctxg, rpb, y);
}

// Round 3
// 278.650 us; speedup vs baseline: 21.2109x; 3.3888x over previous
//
#include <hip/hip_runtime.h>

// Problem constants
constexpr int BN_  = 16;                 // batch
constexpr int SN_  = 577;                // seq
constexpr int SP_  = 640;                // padded seq (multiple of 64)
constexpr int DN_  = 768;                // model dim
constexpr int HN_  = 12;                 // heads
constexpr int HD_  = 64;                 // head dim
constexpr int NB_  = 50;                 // rpe buckets
constexpr int MR_  = BN_ * SN_;          // 9232 rows of x
constexpr int MRP_ = 73 * 128;           // 9344 padded rows
constexpr int NQ_  = 3 * DN_;            // 2304 qkv cols
constexpr int BHS_ = BN_ * HN_ * SN_;    // 110784 (b,h,i) rows
constexpr int SHD_ = SN_ * HD_;          // 36928

typedef __attribute__((ext_vector_type(8))) short short8;
typedef __attribute__((ext_vector_type(4))) float f32x4;

__device__ __forceinline__ short f2bf(float f) {
  union { float f; unsigned u; } v; v.f = f;
  unsigned r = (v.u + 0x7fffu + ((v.u >> 16) & 1u)) >> 16;
  return (short)r;
}

// ---------------------------------------------------------------------------
// Kernel 0: f32 -> bf16 convert (pads dst beyond n_src with zeros)
// ---------------------------------------------------------------------------
__launch_bounds__(256)
__global__ void cvt_k(const float* __restrict__ src, short* __restrict__ dst,
                      int n_src, int n_dst) {
  const int i = (blockIdx.x * 256 + threadIdx.x) * 8;
  if (i >= n_dst) return;
  short8 o;
  if (i < n_src) {
    const float4 a = *(const float4*)(src + i);
    const float4 b = *(const float4*)(src + i + 4);
    union { short8 v; short u[8]; } pk;
    pk.u[0] = f2bf(a.x); pk.u[1] = f2bf(a.y); pk.u[2] = f2bf(a.z); pk.u[3] = f2bf(a.w);
    pk.u[4] = f2bf(b.x); pk.u[5] = f2bf(b.y); pk.u[6] = f2bf(b.z); pk.u[7] = f2bf(b.w);
    o = pk.v;
  } else {
    union { short8 v; short u[8]; } pk;
#pragma unroll
    for (int j = 0; j < 8; ++j) pk.u[j] = 0;
    o = pk.v;
  }
  *(short8*)(dst + i) = o;
}

// ---------------------------------------------------------------------------
// Kernel 1: qkv = x @ w^T in bf16 MFMA. 128x128 tile, BK=64, 4 waves (2x2),
// each wave 64x64 out (4x4 frags of 16x16x32). LDS tiles [128][64] bf16 with
// 16B-unit XOR swizzle (u ^= row&7) -> all b128 LDS ops at minimal cost.
// Epilogue scatters per the torch-faithful reshape into:
//   Q bf16 (scaled 1/8) [bh][i<577][d], K bf16 swizzled [bh][i<640][d],
//   V bf16 [bh][i<640][d].  Each 64-col wave span lies in ONE section.
// ---------------------------------------------------------------------------
__launch_bounds__(256)
__global__ void qkv_mfma_k(const short* __restrict__ xb, const short* __restrict__ wb,
                           short* __restrict__ Qbf, short* __restrict__ Ksw,
                           short* __restrict__ Vbf) {
  __shared__ short At[128 * 64];
  __shared__ short Bt[128 * 64];
  const int t = threadIdx.x;
  const int w = t >> 6, lane = t & 63, g = lane >> 4, ln = lane & 15;
  const int wm = w >> 1, wn = w & 1;
  const int m0 = blockIdx.y * 128, n0 = blockIdx.x * 128;

  // staging: thread t covers row sr = t>>1 (0..127), units su..su+3 (su = (t&1)*4)
  const int sr = t >> 1, su = (t & 1) * 4;
  const short* ga = xb + (size_t)(m0 + sr) * DN_ + su * 8;
  const short* gb = wb + (size_t)(n0 + sr) * DN_ + su * 8;
  short* la = At + sr * 64;
  short* lb = Bt + sr * 64;
  const int swr = sr & 7;

  f32x4 acc[4][4];
#pragma unroll
  for (int mt = 0; mt < 4; ++mt)
#pragma unroll
    for (int nt = 0; nt < 4; ++nt) acc[mt][nt] = (f32x4){0.f, 0.f, 0.f, 0.f};

  for (int k0 = 0; k0 < DN_; k0 += 64) {
    short8 ra[4], rb[4];
#pragma unroll
    for (int u = 0; u < 4; ++u) {
      ra[u] = *(const short8*)(ga + k0 + u * 8);
      rb[u] = *(const short8*)(gb + k0 + u * 8);
    }
    __syncthreads();  // prior iteration's frag reads complete
#pragma unroll
    for (int u = 0; u < 4; ++u) {
      *(short8*)(la + (((su + u) ^ swr) * 8)) = ra[u];
      *(short8*)(lb + (((su + u) ^ swr) * 8)) = rb[u];
    }
    __syncthreads();  // tiles visible
#pragma unroll
    for (int kc = 0; kc < 2; ++kc) {
      short8 af[4], bf[4];
#pragma unroll
      for (int mt = 0; mt < 4; ++mt) {
        const int row = wm * 64 + mt * 16 + ln;
        const int u = (kc * 4 + g) ^ (row & 7);
        af[mt] = *(const short8*)&At[row * 64 + u * 8];
      }
#pragma unroll
      for (int nt = 0; nt < 4; ++nt) {
        const int row = wn * 64 + nt * 16 + ln;
        const int u = (kc * 4 + g) ^ (row & 7);
        bf[nt] = *(const short8*)&Bt[row * 64 + u * 8];
      }
#pragma unroll
      for (int mt = 0; mt < 4; ++mt)
#pragma unroll
        for (int nt = 0; nt < 4; ++nt)
          acc[mt][nt] = __builtin_amdgcn_mfma_f32_16x16x32_bf16(af[mt], bf[nt], acc[mt][nt], 0, 0, 0);
    }
  }

  // epilogue scatter (C layout: row = 4g+r, col = ln per 16x16 frag)
  const int nw0  = n0 + wn * 64;
  const int secg = nw0 / DN_;               // uniform per wave
  const int cbw  = nw0 - secg * DN_;
#pragma unroll
  for (int mt = 0; mt < 4; ++mt) {
#pragma unroll
    for (int r = 0; r < 4; ++r) {
      const int gm = m0 + wm * 64 + mt * 16 + 4 * g + r;
      if (gm >= MR_) continue;
      const int bb = gm / SN_;
      const int ss = gm - bb * SN_;
      const int pb = ss * DN_ + cbw;
#pragma unroll
      for (int nt = 0; nt < 4; ++nt) {
        const int p   = pb + nt * 16 + ln;
        const int hh  = p / SHD_;
        const int rem = p - hh * SHD_;
        const int ii  = rem >> 6;
        const int dd  = rem & 63;
        const size_t ro = (size_t)(bb * HN_ + hh);
        const float v = acc[mt][nt][r];
        if (secg == 0) {
          Qbf[(ro * SN_ + ii) * 64 + dd] = f2bf(v * 0.125f);
        } else if (secg == 1) {
          Ksw[(ro * SP_ + ii) * 64 + (dd ^ ((ii & 7) << 3))] = f2bf(v);
        } else {
          Vbf[(ro * SP_ + ii) * 64 + dd] = f2bf(v);
        }
      }
    }
  }
}

// ---------------------------------------------------------------------------
// Kernel 2: transpose V per (bh): Vbf[j][d] -> Vtsw[d][j], bf16, swizzled
// (short col index ^ ((d&7)<<3)); pad cols j>=577 zeroed.
// ---------------------------------------------------------------------------
__launch_bounds__(256)
__global__ void vtr_k(const short* __restrict__ Vbf, short* __restrict__ Vtsw) {
  __shared__ short T[64][72];
  const int t = threadIdx.x;
  const int jt = blockIdx.x, bh = blockIdx.y;
  const int j0 = jt * 64;
  {
    const int r = t >> 2, c0 = (t & 3) * 16;
    const short* src = Vbf + ((size_t)bh * SP_ + j0 + r) * 64 + c0;
    *(short8*)&T[r][c0]     = *(const short8*)(src);
    *(short8*)&T[r][c0 + 8] = *(const short8*)(src + 8);
  }
  __syncthreads();
  const int d = t >> 2;
  short* dst = Vtsw + ((size_t)bh * 64 + d) * SP_;
  const int sw = (d & 7) << 3;
#pragma unroll
  for (int e = 0; e < 4; ++e) {
    const int jl = (t & 3) * 16 + e * 4;
    const int jg = j0 + jl;
    short4 v;
    v.x = (jg + 0 < SN_) ? T[jl + 0][d] : (short)0;
    v.y = (jg + 1 < SN_) ? T[jl + 1][d] : (short)0;
    v.z = (jg + 2 < SN_) ? T[jl + 2][d] : (short)0;
    v.w = (jg + 3 < SN_) ? T[jl + 3][d] : (short)0;
    *(short4*)&dst[jg ^ sw] = v;
  }
}

// ---------------------------------------------------------------------------
// Kernel 3: MFMA flash attention with iRPE contextual bias, ctx folded in.
// Block = (bh, 64-row q-tile), 4 waves x 16 q-rows. Per block: stage rpe^T as
// bf16 [64][72] once, each wave computes its 16x64 ctx tile with 8 MFMAs into
// per-wave LDS, then the usual K/V flash loop with bias gather.
// ---------------------------------------------------------------------------
__launch_bounds__(256)
__global__ void attn_k(const short* __restrict__ Qbf, const short* __restrict__ Ksw,
                       const short* __restrict__ Vtsw, const float* __restrict__ rpe,
                       const int* __restrict__ rpb, float* __restrict__ y) {
  __shared__ short Kt[64 * 64];          // 8 KB
  __shared__ short Vt[64 * 64];          // 8 KB
  __shared__ short Pt[4][16 * 64];       // 8 KB
  __shared__ short Rp[64][72];           // 9 KB  (rpe^T, bf16, padded)
  __shared__ float ctxs[4][16][68];      // 17.4 KB (per-wave ctx tiles)

  const int t = threadIdx.x;
  const int w = t >> 6, lane = t & 63, g = lane >> 4, ln = lane & 15;
  const int qt = blockIdx.x, bh = blockIdx.y;
  const int b = bh / HN_, h = bh - b * HN_;
  const int i0 = qt * 64;
  const size_t rb = (size_t)bh * SN_;
  const short* Kbh = Ksw + (size_t)bh * SP_ * 64;
  const short* Vbh = Vtsw + (size_t)bh * 64 * SP_;

  // stage rpe^T -> Rp[c][d] (bf16), pad c>=50 with 0
  for (int e = t; e < 64 * 64; e += 256) {
    const int c = e >> 6, d = e & 63;
    Rp[c][d] = (c < NB_) ? f2bf(rpe[d * NB_ + c]) : (short)0;
  }

  // Q fragments (bf16 direct)
  short8 qf[2];
  {
    int row = i0 + 16 * w + ln; if (row > SN_ - 1) row = SN_ - 1;
    const short* qp = Qbf + (rb + row) * 64;
    qf[0] = *(const short8*)(qp + 8 * g);
    qf[1] = *(const short8*)(qp + 32 + 8 * g);
  }

  __syncthreads();  // Rp ready

  // ctx tile: ctx[il][c] = sum_d Q[il][d] * rpe[d][c], via MFMA
  {
    f32x4 accC[4];
#pragma unroll
    for (int ct = 0; ct < 4; ++ct) accC[ct] = (f32x4){0.f, 0.f, 0.f, 0.f};
#pragma unroll
    for (int kc = 0; kc < 2; ++kc) {
#pragma unroll
      for (int ct = 0; ct < 4; ++ct) {
        const short8 rf = *(const short8*)&Rp[ct * 16 + ln][kc * 32 + 8 * g];
        accC[ct] = __builtin_amdgcn_mfma_f32_16x16x32_bf16(qf[kc], rf, accC[ct], 0, 0, 0);
      }
    }
#pragma unroll
    for (int ct = 0; ct < 4; ++ct)
#pragma unroll
      for (int r = 0; r < 4; ++r)
        ctxs[w][4 * g + r][ct * 16 + ln] = accC[ct][r];
  }

  float mrow[4], lrow[4];
#pragma unroll
  for (int r = 0; r < 4; ++r) { mrow[r] = -3e38f; lrow[r] = 0.f; }
  f32x4 accO[4];
#pragma unroll
  for (int dt = 0; dt < 4; ++dt) accO[dt] = (f32x4){0.f, 0.f, 0.f, 0.f};

  for (int jt = 0; jt < 10; ++jt) {
    const int j0 = jt * 64;
    {  // stage K tile + V^T tile (issue loads early, write after barrier)
      const int r = t >> 2, c0 = (t & 3) * 16;
      const short* ks = Kbh + (size_t)(j0 + r) * 64 + c0;
      const short8 k0 = *(const short8*)(ks);
      const short8 k1 = *(const short8*)(ks + 8);
      const short* vs = Vbh + (size_t)r * SP_ + j0 + c0;
      const short8 v0 = *(const short8*)(vs);
      const short8 v1 = *(const short8*)(vs + 8);
      __syncthreads();  // prior step's LDS reads complete
      *(short8*)&Kt[r * 64 + c0]     = k0;
      *(short8*)&Kt[r * 64 + c0 + 8] = k1;
      *(short8*)&Vt[r * 64 + c0]     = v0;
      *(short8*)&Vt[r * 64 + c0 + 8] = v1;
      __syncthreads();
    }

    // QK^T: S tile 16 x 64 per wave
    f32x4 accS[4];
#pragma unroll
    for (int nt = 0; nt < 4; ++nt) accS[nt] = (f32x4){0.f, 0.f, 0.f, 0.f};
#pragma unroll
    for (int kc = 0; kc < 2; ++kc) {
      const int cb = (kc * 32 + 8 * g) ^ ((ln & 7) << 3);
#pragma unroll
      for (int nt = 0; nt < 4; ++nt) {
        const short8 kf = *(const short8*)&Kt[(nt * 16 + ln) * 64 + cb];
        accS[nt] = __builtin_amdgcn_mfma_f32_16x16x32_bf16(qf[kc], kf, accS[nt], 0, 0, 0);
      }
    }

    // bias + mask
    float pv[4][4];
#pragma unroll
    for (int nt = 0; nt < 4; ++nt) {
      const int jg = j0 + nt * 16 + ln;
#pragma unroll
      for (int r = 0; r < 4; ++r) {
        float sv = accS[nt][r];
        if (jg < SN_) {
          int irow = i0 + 16 * w + 4 * g + r; if (irow > SN_ - 1) irow = SN_ - 1;
          sv += ctxs[w][4 * g + r][rpb[irow * SN_ + jg]];
        } else {
          sv = -3e38f;
        }
        pv[nt][r] = sv;
      }
    }

    // online softmax (row = 4g+r lives in one 16-lane group)
#pragma unroll
    for (int r = 0; r < 4; ++r) {
      float mx = fmaxf(fmaxf(pv[0][r], pv[1][r]), fmaxf(pv[2][r], pv[3][r]));
#pragma unroll
      for (int msk = 8; msk >= 1; msk >>= 1) mx = fmaxf(mx, __shfl_xor(mx, msk));
      const float mnew = fmaxf(mrow[r], mx);
      const float sc = __expf(mrow[r] - mnew);
      mrow[r] = mnew;
      float sum = 0.f;
#pragma unroll
      for (int nt = 0; nt < 4; ++nt) {
        pv[nt][r] = __expf(pv[nt][r] - mnew);
        sum += pv[nt][r];
      }
#pragma unroll
      for (int msk = 8; msk >= 1; msk >>= 1) sum += __shfl_xor(sum, msk);
      lrow[r] = lrow[r] * sc + sum;
#pragma unroll
      for (int dt = 0; dt < 4; ++dt) accO[dt][r] *= sc;
      const int il = 4 * g + r;
      const int swp = (il & 7) << 3;
#pragma unroll
      for (int nt = 0; nt < 4; ++nt)
        Pt[w][il * 64 + ((nt * 16 + ln) ^ swp)] = f2bf(pv[nt][r]);
    }

    // PV: O += P . V  (P per-wave in LDS; same-wave RAW, no barrier)
#pragma unroll
    for (int kc = 0; kc < 2; ++kc) {
      const int cb = (kc * 32 + 8 * g) ^ ((ln & 7) << 3);
      const short8 pf = *(const short8*)&Pt[w][ln * 64 + cb];
#pragma unroll
      for (int dt = 0; dt < 4; ++dt) {
        const short8 vf = *(const short8*)&Vt[(dt * 16 + ln) * 64 + cb];
        accO[dt] = __builtin_amdgcn_mfma_f32_16x16x32_bf16(pf, vf, accO[dt], 0, 0, 0);
      }
    }
  }

  // epilogue: y[b, i, h*64 + d] = O / l
#pragma unroll
  for (int r = 0; r < 4; ++r) {
    const int i = i0 + 16 * w + 4 * g + r;
    if (i >= SN_) continue;
    const float inv = 1.f / lrow[r];
    float* yp = y + ((size_t)b * SN_ + i) * DN_ + h * HD_ + ln;
#pragma unroll
    for (int dt = 0; dt < 4; ++dt) yp[dt * 16] = accO[dt][r] * inv;
  }
}

// ---------------------------------------------------------------------------
extern "C" void kernel_launch(void* const* d_in, const int* in_sizes, int n_in,
                              void* d_out, int out_size, void* d_ws, size_t ws_size,
                              hipStream_t stream) {
  const float* x   = (const float*)d_in[0];
  const float* w   = (const float*)d_in[1];
  const float* rpe = (const float*)d_in[2];
  const int*   rpb = (const int*)d_in[3];
  float* y = (float*)d_out;

  short* xb   = (short*)d_ws;                      // 9344*768
  short* wb   = xb + (size_t)MRP_ * DN_;           // 2304*768
  short* Qbf  = wb + (size_t)NQ_ * DN_;            // 110784*64
  short* Ksw  = Qbf + (size_t)BHS_ * HD_;          // 192*640*64
  short* Vbf  = Ksw + (size_t)BN_ * HN_ * SP_ * 64;
  short* Vtsw = Vbf + (size_t)BN_ * HN_ * SP_ * 64;

  cvt_k<<<dim3(MRP_ * DN_ / 2048), 256, 0, stream>>>(x, xb, MR_ * DN_, MRP_ * DN_);
  cvt_k<<<dim3(NQ_ * DN_ / 2048), 256, 0, stream>>>(w, wb, NQ_ * DN_, NQ_ * DN_);
  qkv_mfma_k<<<dim3(18, 73), 256, 0, stream>>>(xb, wb, Qbf, Ksw, Vbf);
  vtr_k<<<dim3(10, BN_ * HN_), 256, 0, stream>>>(Vbf, Vtsw);
  attn_k<<<dim3(10, BN_ * HN_), 256, 0, stream>>>(Qbf, Ksw, Vtsw, rpe, rpb, y);
}

// Round 4
// 173.154 us; speedup vs baseline: 34.1340x; 1.6093x over previous
//
#include <hip/hip_runtime.h>

// Problem constants
constexpr int BN_  = 16;                 // batch
constexpr int SN_  = 577;                // seq
constexpr int SP_  = 640;                // padded seq (multiple of 64)
constexpr int DN_  = 768;                // model dim
constexpr int HN_  = 12;                 // heads
constexpr int HD_  = 64;                 // head dim
constexpr int NB_  = 50;                 // rpe buckets
constexpr int MR_  = BN_ * SN_;          // 9232 rows of x
constexpr int MRP_ = 73 * 128;           // 9344 padded rows
constexpr int NQ_  = 3 * DN_;            // 2304 qkv cols
constexpr int BHS_ = BN_ * HN_ * SN_;    // 110784 (b,h,i) rows
constexpr int SHD_ = SN_ * HD_;          // 36928

typedef __attribute__((ext_vector_type(8))) short short8;
typedef __attribute__((ext_vector_type(4))) float f32x4;

__device__ __forceinline__ short f2bf(float f) {
  union { float f; unsigned u; } v; v.f = f;
  unsigned r = (v.u + 0x7fffu + ((v.u >> 16) & 1u)) >> 16;
  return (short)r;
}

// ---------------------------------------------------------------------------
// Kernel 0: f32 -> bf16 convert (pads dst beyond n_src with zeros)
// ---------------------------------------------------------------------------
__launch_bounds__(256)
__global__ void cvt_k(const float* __restrict__ src, short* __restrict__ dst,
                      int n_src, int n_dst) {
  const int i = (blockIdx.x * 256 + threadIdx.x) * 8;
  if (i >= n_dst) return;
  union { short8 v; short u[8]; } pk;
  if (i < n_src) {
    const float4 a = *(const float4*)(src + i);
    const float4 b = *(const float4*)(src + i + 4);
    pk.u[0] = f2bf(a.x); pk.u[1] = f2bf(a.y); pk.u[2] = f2bf(a.z); pk.u[3] = f2bf(a.w);
    pk.u[4] = f2bf(b.x); pk.u[5] = f2bf(b.y); pk.u[6] = f2bf(b.z); pk.u[7] = f2bf(b.w);
  } else {
#pragma unroll
    for (int j = 0; j < 8; ++j) pk.u[j] = 0;
  }
  *(short8*)(dst + i) = pk.v;
}

// ---------------------------------------------------------------------------
// Kernel 0b: rp_bucket int32 [577][577] -> u8 [577][640] (pad j with 0)
// ---------------------------------------------------------------------------
__launch_bounds__(256)
__global__ void rpb8_k(const int* __restrict__ rpb, unsigned char* __restrict__ rpbu8) {
  const int tid = blockIdx.x * 256 + threadIdx.x;
  if (tid >= SN_ * 160) return;
  const int i = tid / 160, c4 = tid - i * 160;
  const int j = c4 * 4;
  uchar4 o;
  o.x = (j     < SN_) ? (unsigned char)rpb[i * SN_ + j    ] : 0;
  o.y = (j + 1 < SN_) ? (unsigned char)rpb[i * SN_ + j + 1] : 0;
  o.z = (j + 2 < SN_) ? (unsigned char)rpb[i * SN_ + j + 2] : 0;
  o.w = (j + 3 < SN_) ? (unsigned char)rpb[i * SN_ + j + 3] : 0;
  *(uchar4*)(rpbu8 + (size_t)i * 640 + j) = o;
}

// ---------------------------------------------------------------------------
// Kernel 1: qkv = x @ w^T in bf16 MFMA. 128x128 tile, BK=64, 4 waves (2x2),
// with next-K-tile register prefetch. Epilogue scatters (torch-faithful
// reshape) into Q bf16 (scaled 1/8), K bf16 swizzled, V bf16.
// ---------------------------------------------------------------------------
__launch_bounds__(256)
__global__ void qkv_mfma_k(const short* __restrict__ xb, const short* __restrict__ wb,
                           short* __restrict__ Qbf, short* __restrict__ Ksw,
                           short* __restrict__ Vbf) {
  __shared__ short At[128 * 64];
  __shared__ short Bt[128 * 64];
  const int t = threadIdx.x;
  const int w = t >> 6, lane = t & 63, g = lane >> 4, ln = lane & 15;
  const int wm = w >> 1, wn = w & 1;
  const int m0 = blockIdx.y * 128, n0 = blockIdx.x * 128;

  const int sr = t >> 1, su = (t & 1) * 4;
  const short* ga = xb + (size_t)(m0 + sr) * DN_ + su * 8;
  const short* gb = wb + (size_t)(n0 + sr) * DN_ + su * 8;
  short* la = At + sr * 64;
  short* lb = Bt + sr * 64;
  const int swr = sr & 7;

  f32x4 acc[4][4];
#pragma unroll
  for (int mt = 0; mt < 4; ++mt)
#pragma unroll
    for (int nt = 0; nt < 4; ++nt) acc[mt][nt] = (f32x4){0.f, 0.f, 0.f, 0.f};

  short8 ra[4], rb[4];
#pragma unroll
  for (int u = 0; u < 4; ++u) {
    ra[u] = *(const short8*)(ga + u * 8);
    rb[u] = *(const short8*)(gb + u * 8);
  }

  for (int k0 = 0; k0 < DN_; k0 += 64) {
    __syncthreads();  // prior iteration's frag reads complete
#pragma unroll
    for (int u = 0; u < 4; ++u) {
      *(short8*)(la + (((su + u) ^ swr) * 8)) = ra[u];
      *(short8*)(lb + (((su + u) ^ swr) * 8)) = rb[u];
    }
    __syncthreads();  // tiles visible
    if (k0 + 64 < DN_) {
#pragma unroll
      for (int u = 0; u < 4; ++u) {
        ra[u] = *(const short8*)(ga + k0 + 64 + u * 8);
        rb[u] = *(const short8*)(gb + k0 + 64 + u * 8);
      }
    }
#pragma unroll
    for (int kc = 0; kc < 2; ++kc) {
      short8 af[4], bf[4];
#pragma unroll
      for (int mt = 0; mt < 4; ++mt) {
        const int row = wm * 64 + mt * 16 + ln;
        const int u = (kc * 4 + g) ^ (row & 7);
        af[mt] = *(const short8*)&At[row * 64 + u * 8];
      }
#pragma unroll
      for (int nt = 0; nt < 4; ++nt) {
        const int row = wn * 64 + nt * 16 + ln;
        const int u = (kc * 4 + g) ^ (row & 7);
        bf[nt] = *(const short8*)&Bt[row * 64 + u * 8];
      }
#pragma unroll
      for (int mt = 0; mt < 4; ++mt)
#pragma unroll
        for (int nt = 0; nt < 4; ++nt)
          acc[mt][nt] = __builtin_amdgcn_mfma_f32_16x16x32_bf16(af[mt], bf[nt], acc[mt][nt], 0, 0, 0);
    }
  }

  const int nw0  = n0 + wn * 64;
  const int secg = nw0 / DN_;               // uniform per wave
  const int cbw  = nw0 - secg * DN_;
#pragma unroll
  for (int mt = 0; mt < 4; ++mt) {
#pragma unroll
    for (int r = 0; r < 4; ++r) {
      const int gm = m0 + wm * 64 + mt * 16 + 4 * g + r;
      if (gm >= MR_) continue;
      const int bb = gm / SN_;
      const int ss = gm - bb * SN_;
      const int pb = ss * DN_ + cbw;
#pragma unroll
      for (int nt = 0; nt < 4; ++nt) {
        const int p   = pb + nt * 16 + ln;
        const int hh  = p / SHD_;
        const int rem = p - hh * SHD_;
        const int ii  = rem >> 6;
        const int dd  = rem & 63;
        const size_t ro = (size_t)(bb * HN_ + hh);
        const float v = acc[mt][nt][r];
        if (secg == 0) {
          Qbf[(ro * SN_ + ii) * 64 + dd] = f2bf(v * 0.125f);
        } else if (secg == 1) {
          Ksw[(ro * SP_ + ii) * 64 + (dd ^ ((ii & 7) << 3))] = f2bf(v);
        } else {
          Vbf[(ro * SP_ + ii) * 64 + dd] = f2bf(v);
        }
      }
    }
  }
}

// ---------------------------------------------------------------------------
// Kernel 2: transpose V per (bh): Vbf[j][d] -> Vtsw[d][j], bf16, swizzled
// (short col index ^ ((d&7)<<3)); pad cols j>=577 zeroed.
// ---------------------------------------------------------------------------
__launch_bounds__(256)
__global__ void vtr_k(const short* __restrict__ Vbf, short* __restrict__ Vtsw) {
  __shared__ short T[64][72];
  const int t = threadIdx.x;
  const int jt = blockIdx.x, bh = blockIdx.y;
  const int j0 = jt * 64;
  {
    const int r = t >> 2, c0 = (t & 3) * 16;
    const short* src = Vbf + ((size_t)bh * SP_ + j0 + r) * 64 + c0;
    *(short8*)&T[r][c0]     = *(const short8*)(src);
    *(short8*)&T[r][c0 + 8] = *(const short8*)(src + 8);
  }
  __syncthreads();
  const int d = t >> 2;
  short* dst = Vtsw + ((size_t)bh * 64 + d) * SP_;
  const int sw = (d & 7) << 3;
#pragma unroll
  for (int e = 0; e < 4; ++e) {
    const int jl = (t & 3) * 16 + e * 4;
    const int jg = j0 + jl;
    short4 v;
    v.x = (jg + 0 < SN_) ? T[jl + 0][d] : (short)0;
    v.y = (jg + 1 < SN_) ? T[jl + 1][d] : (short)0;
    v.z = (jg + 2 < SN_) ? T[jl + 2][d] : (short)0;
    v.w = (jg + 3 < SN_) ? T[jl + 3][d] : (short)0;
    *(short4*)&dst[jg ^ sw] = v;
  }
}

// ---------------------------------------------------------------------------
// Kernel 3: MFMA flash attention, swapped-QK in-register softmax.
// Block = (bh, 64-row q-tile), 4 waves x 16 q-rows.
// QK^T computed as mfma(K,Q) -> lane ln holds full S row (i=ln) in 16 regs
// (j = 16nt+4g+r). Softmax: 15 in-reg ops + 2 shfl. P packed to bf16 in
// registers, fed as PV A-operand with matching slot map
// sigma'(g,jj) = kc*32 + 16*(jj>>2) + 4g + (jj&3)  (bijective per kc).
// rpb staged per-jt as u8 LDS tile; K/V/rpb register-prefetched (T14).
// ---------------------------------------------------------------------------
__launch_bounds__(256)
__global__ void attn_k(const short* __restrict__ Qbf, const short* __restrict__ Ksw,
                       const short* __restrict__ Vtsw, const float* __restrict__ rpe,
                       const unsigned char* __restrict__ rpbu8, float* __restrict__ y) {
  __shared__ short Kt[64 * 64];          // 8 KB
  __shared__ short Vt[64 * 64];          // 8 KB
  __shared__ float ctxs[4][16][68];      // 17.4 KB (per-wave ctx tiles)
  __shared__ char urp[64 * 72 * 2];      // 9 KB union: Rp[64][72] short | rpbt[64*80] u8
  short (*Rp)[72] = (short (*)[72])urp;
  unsigned char* rpbt = (unsigned char*)urp;

  const int t = threadIdx.x;
  const int w = t >> 6, lane = t & 63, g = lane >> 4, ln = lane & 15;
  const int qt = blockIdx.x, bh = blockIdx.y;
  const int b = bh / HN_, h = bh - b * HN_;
  const int i0 = qt * 64;
  const size_t rb = (size_t)bh * SN_;
  const short* Kbh = Ksw + (size_t)bh * SP_ * 64;
  const short* Vbh = Vtsw + (size_t)bh * 64 * SP_;

  // staging thread map (shared by K, V, rpb tiles)
  const int sr_ = t >> 2, scu_ = (t & 3) * 16;
  const int irow_s = (i0 + sr_ <= SN_ - 1) ? (i0 + sr_) : (SN_ - 1);

  // prefetch tile jt=0 (overlaps Rp staging + ctx MFMA)
  short8 kr0, kr1, vr0, vr1; int4 rp_;
  {
    const short* ks = Kbh + (size_t)sr_ * 64 + scu_;
    kr0 = *(const short8*)(ks); kr1 = *(const short8*)(ks + 8);
    const short* vs = Vbh + (size_t)sr_ * SP_ + scu_;
    vr0 = *(const short8*)(vs); vr1 = *(const short8*)(vs + 8);
    rp_ = *(const int4*)(rpbu8 + (size_t)irow_s * 640 + scu_);
  }

  // stage rpe^T -> Rp[c][d] (bf16), pad c>=50 with 0
  for (int e = t; e < 64 * 64; e += 256) {
    const int c = e >> 6, d = e & 63;
    Rp[c][d] = (c < NB_) ? f2bf(rpe[d * NB_ + c]) : (short)0;
  }

  // Q fragments (bf16 direct); lane holds Q row i = i0 + 16w + ln
  short8 qf[2];
  {
    int row = i0 + 16 * w + ln; if (row > SN_ - 1) row = SN_ - 1;
    const short* qp = Qbf + (rb + row) * 64;
    qf[0] = *(const short8*)(qp + 8 * g);
    qf[1] = *(const short8*)(qp + 32 + 8 * g);
  }

  __syncthreads();  // Rp ready

  // ctx tile: ctx[i_local=4g+r][c=ct*16+ln] via mfma(qf, rf)
  {
    f32x4 accC[4];
#pragma unroll
    for (int ct = 0; ct < 4; ++ct) accC[ct] = (f32x4){0.f, 0.f, 0.f, 0.f};
#pragma unroll
    for (int kc = 0; kc < 2; ++kc) {
#pragma unroll
      for (int ct = 0; ct < 4; ++ct) {
        const short8 rf = *(const short8*)&Rp[ct * 16 + ln][kc * 32 + 8 * g];
        accC[ct] = __builtin_amdgcn_mfma_f32_16x16x32_bf16(qf[kc], rf, accC[ct], 0, 0, 0);
      }
    }
#pragma unroll
    for (int ct = 0; ct < 4; ++ct)
#pragma unroll
      for (int r = 0; r < 4; ++r)
        ctxs[w][4 * g + r][ct * 16 + ln] = accC[ct][r];
  }

  float m = -3e38f, l = 0.f;
  f32x4 accO[4];
#pragma unroll
  for (int dt = 0; dt < 4; ++dt) accO[dt] = (f32x4){0.f, 0.f, 0.f, 0.f};

  const int swv = (ln & 7) << 3;

  for (int jt = 0; jt < 10; ++jt) {
    const int j0 = jt * 64;
    __syncthreads();  // previous tile's LDS reads (and Rp reads, 1st iter) done
    *(short8*)&Kt[sr_ * 64 + scu_]     = kr0;
    *(short8*)&Kt[sr_ * 64 + scu_ + 8] = kr1;
    *(short8*)&Vt[sr_ * 64 + scu_]     = vr0;
    *(short8*)&Vt[sr_ * 64 + scu_ + 8] = vr1;
    *(int4*)&rpbt[sr_ * 80 + scu_]     = rp_;
    __syncthreads();  // tiles visible

    if (jt < 9) {  // prefetch next tile (latency hides under compute)
      const int jn = j0 + 64;
      const short* ks = Kbh + (size_t)(jn + sr_) * 64 + scu_;
      kr0 = *(const short8*)(ks); kr1 = *(const short8*)(ks + 8);
      const short* vs = Vbh + (size_t)sr_ * SP_ + jn + scu_;
      vr0 = *(const short8*)(vs); vr1 = *(const short8*)(vs + 8);
      rp_ = *(const int4*)(rpbu8 + (size_t)irow_s * 640 + jn + scu_);
    }

    // QK^T swapped: accS[nt][r] = S[i = ln][j = j0 + nt*16 + 4g + r]
    f32x4 accS[4];
#pragma unroll
    for (int nt = 0; nt < 4; ++nt) accS[nt] = (f32x4){0.f, 0.f, 0.f, 0.f};
#pragma unroll
    for (int kc = 0; kc < 2; ++kc) {
      const int cb = (kc * 32 + 8 * g) ^ swv;
#pragma unroll
      for (int nt = 0; nt < 4; ++nt) {
        const short8 kf = *(const short8*)&Kt[(nt * 16 + ln) * 64 + cb];
        accS[nt] = __builtin_amdgcn_mfma_f32_16x16x32_bf16(kf, qf[kc], accS[nt], 0, 0, 0);
      }
    }

    // bias + mask (bucket via u8 LDS tile; ctx via per-wave LDS row ln)
    float p[4][4];
#pragma unroll
    for (int nt = 0; nt < 4; ++nt) {
      const uchar4 bk = *(const uchar4*)&rpbt[(16 * w + ln) * 80 + nt * 16 + 4 * g];
      const int jb = j0 + nt * 16 + 4 * g;
      p[nt][0] = (jb     < SN_) ? accS[nt][0] + ctxs[w][ln][bk.x] : -3e38f;
      p[nt][1] = (jb + 1 < SN_) ? accS[nt][1] + ctxs[w][ln][bk.y] : -3e38f;
      p[nt][2] = (jb + 2 < SN_) ? accS[nt][2] + ctxs[w][ln][bk.z] : -3e38f;
      p[nt][3] = (jb + 3 < SN_) ? accS[nt][3] + ctxs[w][ln][bk.w] : -3e38f;
    }

    // online softmax, in-register row (i = ln)
    float mx = -3e38f;
#pragma unroll
    for (int nt = 0; nt < 4; ++nt)
      mx = fmaxf(mx, fmaxf(fmaxf(p[nt][0], p[nt][1]), fmaxf(p[nt][2], p[nt][3])));
    mx = fmaxf(mx, __shfl_xor(mx, 16));
    mx = fmaxf(mx, __shfl_xor(mx, 32));
    const float mnew = fmaxf(m, mx);
    const float sc = __expf(m - mnew);
    m = mnew;
    float sum = 0.f;
#pragma unroll
    for (int nt = 0; nt < 4; ++nt)
#pragma unroll
      for (int r = 0; r < 4; ++r) {
        p[nt][r] = __expf(p[nt][r] - mnew);
        sum += p[nt][r];
      }
    sum += __shfl_xor(sum, 16);
    sum += __shfl_xor(sum, 32);
    l = l * sc + sum;

    // rescale accO (rows i = 4g+r need that row's sc)
    float scr[4];
#pragma unroll
    for (int r = 0; r < 4; ++r) scr[r] = __shfl(sc, 4 * g + r);
#pragma unroll
    for (int dt = 0; dt < 4; ++dt)
#pragma unroll
      for (int r = 0; r < 4; ++r) accO[dt][r] *= scr[r];

    // pack P to bf16 in registers (slot jj -> j = kc*32 + 16*(jj>>2) + 4g + (jj&3))
    short8 pf[2];
#pragma unroll
    for (int kc = 0; kc < 2; ++kc) {
      union { short8 v; short u[8]; } pk;
#pragma unroll
      for (int r = 0; r < 4; ++r) {
        pk.u[r]     = f2bf(p[2 * kc][r]);
        pk.u[4 + r] = f2bf(p[2 * kc + 1][r]);
      }
      pf[kc] = pk.v;
    }

    // PV: accO[dt][r] = O[i=4g+r][d=dt*16+ln]; V^T read with matching slot map
#pragma unroll
    for (int kc = 0; kc < 2; ++kc) {
#pragma unroll
      for (int dt = 0; dt < 4; ++dt) {
        const short* vrow = &Vt[(dt * 16 + ln) * 64];
        union { short8 v; short4 h[2]; } u;
        u.h[0] = *(const short4*)&vrow[(kc * 32 + 4 * g) ^ swv];
        u.h[1] = *(const short4*)&vrow[(kc * 32 + 16 + 4 * g) ^ swv];
        accO[dt] = __builtin_amdgcn_mfma_f32_16x16x32_bf16(pf[kc], u.v, accO[dt], 0, 0, 0);
      }
    }
  }

  // epilogue: y[b, i, h*64 + d] = O / l   (l for row 4g+r via shfl)
  float linv[4];
#pragma unroll
  for (int r = 0; r < 4; ++r) linv[r] = 1.f / __shfl(l, 4 * g + r);
#pragma unroll
  for (int r = 0; r < 4; ++r) {
    const int i = i0 + 16 * w + 4 * g + r;
    if (i >= SN_) continue;
    float* yp = y + ((size_t)b * SN_ + i) * DN_ + h * HD_ + ln;
#pragma unroll
    for (int dt = 0; dt < 4; ++dt) yp[dt * 16] = accO[dt][r] * linv[r];
  }
}

// ---------------------------------------------------------------------------
extern "C" void kernel_launch(void* const* d_in, const int* in_sizes, int n_in,
                              void* d_out, int out_size, void* d_ws, size_t ws_size,
                              hipStream_t stream) {
  const float* x   = (const float*)d_in[0];
  const float* w   = (const float*)d_in[1];
  const float* rpe = (const float*)d_in[2];
  const int*   rpb = (const int*)d_in[3];
  float* y = (float*)d_out;

  short* xb   = (short*)d_ws;                      // 9344*768
  short* wb   = xb + (size_t)MRP_ * DN_;           // 2304*768
  short* Qbf  = wb + (size_t)NQ_ * DN_;            // 110784*64
  short* Ksw  = Qbf + (size_t)BHS_ * HD_;          // 192*640*64
  short* Vbf  = Ksw + (size_t)BN_ * HN_ * SP_ * 64;
  short* Vtsw = Vbf + (size_t)BN_ * HN_ * SP_ * 64;
  unsigned char* rpbu8 = (unsigned char*)(Vtsw + (size_t)BN_ * HN_ * 64 * SP_);  // 577*640

  cvt_k<<<dim3(MRP_ * DN_ / 2048), 256, 0, stream>>>(x, xb, MR_ * DN_, MRP_ * DN_);
  cvt_k<<<dim3(NQ_ * DN_ / 2048), 256, 0, stream>>>(w, wb, NQ_ * DN_, NQ_ * DN_);
  rpb8_k<<<dim3((SN_ * 160 + 255) / 256), 256, 0, stream>>>(rpb, rpbu8);
  qkv_mfma_k<<<dim3(18, 73), 256, 0, stream>>>(xb, wb, Qbf, Ksw, Vbf);
  vtr_k<<<dim3(10, BN_ * HN_), 256, 0, stream>>>(Vbf, Vtsw);
  attn_k<<<dim3(10, BN_ * HN_), 256, 0, stream>>>(Qbf, Ksw, Vtsw, rpe, rpbu8, y);
}

// Round 5
// 160.446 us; speedup vs baseline: 36.8375x; 1.0792x over previous
//
#include <hip/hip_runtime.h>

// Problem constants
constexpr int BN_  = 16;                 // batch
constexpr int SN_  = 577;                // seq
constexpr int SP_  = 640;                // padded seq (multiple of 64)
constexpr int DN_  = 768;                // model dim
constexpr int HN_  = 12;                 // heads
constexpr int HD_  = 64;                 // head dim
constexpr int NB_  = 50;                 // rpe buckets
constexpr int MR_  = BN_ * SN_;          // 9232 rows of x
constexpr int MRP_ = 73 * 128;           // 9344 padded rows
constexpr int NQ_  = 3 * DN_;            // 2304 qkv cols
constexpr int BHS_ = BN_ * HN_ * SN_;    // 110784 (b,h,i) rows
constexpr int SHD_ = SN_ * HD_;          // 36928

typedef __attribute__((ext_vector_type(8))) short short8;
typedef __attribute__((ext_vector_type(4))) float f32x4;

__device__ __forceinline__ short f2bf(float f) {
  union { float f; unsigned u; } v; v.f = f;
  unsigned r = (v.u + 0x7fffu + ((v.u >> 16) & 1u)) >> 16;
  return (short)r;
}

// raw v_exp_f32: D = 2^S0 (handles -3e38 -> 0)
__device__ __forceinline__ float ex2(float x) {
  float r; asm("v_exp_f32 %0, %1" : "=v"(r) : "v"(x)); return r;
}

// ---------------------------------------------------------------------------
// Kernel 0: f32 -> bf16 convert (pads dst beyond n_src with zeros)
// ---------------------------------------------------------------------------
__launch_bounds__(256)
__global__ void cvt_k(const float* __restrict__ src, short* __restrict__ dst,
                      int n_src, int n_dst) {
  const int i = (blockIdx.x * 256 + threadIdx.x) * 8;
  if (i >= n_dst) return;
  union { short8 v; short u[8]; } pk;
  if (i < n_src) {
    const float4 a = *(const float4*)(src + i);
    const float4 b = *(const float4*)(src + i + 4);
    pk.u[0] = f2bf(a.x); pk.u[1] = f2bf(a.y); pk.u[2] = f2bf(a.z); pk.u[3] = f2bf(a.w);
    pk.u[4] = f2bf(b.x); pk.u[5] = f2bf(b.y); pk.u[6] = f2bf(b.z); pk.u[7] = f2bf(b.w);
  } else {
#pragma unroll
    for (int j = 0; j < 8; ++j) pk.u[j] = 0;
  }
  *(short8*)(dst + i) = pk.v;
}

// ---------------------------------------------------------------------------
// Kernel 0b: rp_bucket int32 [577][577] -> u8 [577][640] (pad j with 0)
// ---------------------------------------------------------------------------
__launch_bounds__(256)
__global__ void rpb8_k(const int* __restrict__ rpb, unsigned char* __restrict__ rpbu8) {
  const int tid = blockIdx.x * 256 + threadIdx.x;
  if (tid >= SN_ * 160) return;
  const int i = tid / 160, c4 = tid - i * 160;
  const int j = c4 * 4;
  uchar4 o;
  o.x = (j     < SN_) ? (unsigned char)rpb[i * SN_ + j    ] : 0;
  o.y = (j + 1 < SN_) ? (unsigned char)rpb[i * SN_ + j + 1] : 0;
  o.z = (j + 2 < SN_) ? (unsigned char)rpb[i * SN_ + j + 2] : 0;
  o.w = (j + 3 < SN_) ? (unsigned char)rpb[i * SN_ + j + 3] : 0;
  *(uchar4*)(rpbu8 + (size_t)i * 640 + j) = o;
}

// ---------------------------------------------------------------------------
// Kernel 1: qkv = x @ w^T in bf16 MFMA. 128x128 tile, BK=64, 4 waves (2x2),
// with next-K-tile register prefetch. Epilogue scatters (torch-faithful
// reshape) into Q bf16 (scaled log2e/8 -> exp2-domain softmax), K bf16
// swizzled, V bf16.
// ---------------------------------------------------------------------------
__launch_bounds__(256)
__global__ void qkv_mfma_k(const short* __restrict__ xb, const short* __restrict__ wb,
                           short* __restrict__ Qbf, short* __restrict__ Ksw,
                           short* __restrict__ Vbf) {
  __shared__ short At[128 * 64];
  __shared__ short Bt[128 * 64];
  const int t = threadIdx.x;
  const int w = t >> 6, lane = t & 63, g = lane >> 4, ln = lane & 15;
  const int wm = w >> 1, wn = w & 1;
  const int m0 = blockIdx.y * 128, n0 = blockIdx.x * 128;

  const int sr = t >> 1, su = (t & 1) * 4;
  const short* ga = xb + (size_t)(m0 + sr) * DN_ + su * 8;
  const short* gb = wb + (size_t)(n0 + sr) * DN_ + su * 8;
  short* la = At + sr * 64;
  short* lb = Bt + sr * 64;
  const int swr = sr & 7;

  f32x4 acc[4][4];
#pragma unroll
  for (int mt = 0; mt < 4; ++mt)
#pragma unroll
    for (int nt = 0; nt < 4; ++nt) acc[mt][nt] = (f32x4){0.f, 0.f, 0.f, 0.f};

  short8 ra[4], rb[4];
#pragma unroll
  for (int u = 0; u < 4; ++u) {
    ra[u] = *(const short8*)(ga + u * 8);
    rb[u] = *(const short8*)(gb + u * 8);
  }

  for (int k0 = 0; k0 < DN_; k0 += 64) {
    __syncthreads();  // prior iteration's frag reads complete
#pragma unroll
    for (int u = 0; u < 4; ++u) {
      *(short8*)(la + (((su + u) ^ swr) * 8)) = ra[u];
      *(short8*)(lb + (((su + u) ^ swr) * 8)) = rb[u];
    }
    __syncthreads();  // tiles visible
    if (k0 + 64 < DN_) {
#pragma unroll
      for (int u = 0; u < 4; ++u) {
        ra[u] = *(const short8*)(ga + k0 + 64 + u * 8);
        rb[u] = *(const short8*)(gb + k0 + 64 + u * 8);
      }
    }
#pragma unroll
    for (int kc = 0; kc < 2; ++kc) {
      short8 af[4], bf[4];
#pragma unroll
      for (int mt = 0; mt < 4; ++mt) {
        const int row = wm * 64 + mt * 16 + ln;
        const int u = (kc * 4 + g) ^ (row & 7);
        af[mt] = *(const short8*)&At[row * 64 + u * 8];
      }
#pragma unroll
      for (int nt = 0; nt < 4; ++nt) {
        const int row = wn * 64 + nt * 16 + ln;
        const int u = (kc * 4 + g) ^ (row & 7);
        bf[nt] = *(const short8*)&Bt[row * 64 + u * 8];
      }
#pragma unroll
      for (int mt = 0; mt < 4; ++mt)
#pragma unroll
        for (int nt = 0; nt < 4; ++nt)
          acc[mt][nt] = __builtin_amdgcn_mfma_f32_16x16x32_bf16(af[mt], bf[nt], acc[mt][nt], 0, 0, 0);
    }
  }

  const int nw0  = n0 + wn * 64;
  const int secg = nw0 / DN_;               // uniform per wave
  const int cbw  = nw0 - secg * DN_;
  const float QSC = 0.18033688011112042f;   // log2(e) / 8
#pragma unroll
  for (int mt = 0; mt < 4; ++mt) {
#pragma unroll
    for (int r = 0; r < 4; ++r) {
      const int gm = m0 + wm * 64 + mt * 16 + 4 * g + r;
      if (gm >= MR_) continue;
      const int bb = gm / SN_;
      const int ss = gm - bb * SN_;
      const int pb = ss * DN_ + cbw;
#pragma unroll
      for (int nt = 0; nt < 4; ++nt) {
        const int p   = pb + nt * 16 + ln;
        const int hh  = p / SHD_;
        const int rem = p - hh * SHD_;
        const int ii  = rem >> 6;
        const int dd  = rem & 63;
        const size_t ro = (size_t)(bb * HN_ + hh);
        const float v = acc[mt][nt][r];
        if (secg == 0) {
          Qbf[(ro * SN_ + ii) * 64 + dd] = f2bf(v * QSC);
        } else if (secg == 1) {
          Ksw[(ro * SP_ + ii) * 64 + (dd ^ ((ii & 7) << 3))] = f2bf(v);
        } else {
          Vbf[(ro * SP_ + ii) * 64 + dd] = f2bf(v);
        }
      }
    }
  }
}

// ---------------------------------------------------------------------------
// Kernel 2: transpose V per (bh): Vbf[j][d] -> Vtsw[d][j], bf16, swizzled
// (short col index ^ ((d&7)<<3)); pad cols j>=577 zeroed (required: PV must
// never multiply into poison/NaN memory).
// ---------------------------------------------------------------------------
__launch_bounds__(256)
__global__ void vtr_k(const short* __restrict__ Vbf, short* __restrict__ Vtsw) {
  __shared__ short T[64][72];
  const int t = threadIdx.x;
  const int jt = blockIdx.x, bh = blockIdx.y;
  const int j0 = jt * 64;
  {
    const int r = t >> 2, c0 = (t & 3) * 16;
    const short* src = Vbf + ((size_t)bh * SP_ + j0 + r) * 64 + c0;
    *(short8*)&T[r][c0]     = *(const short8*)(src);
    *(short8*)&T[r][c0 + 8] = *(const short8*)(src + 8);
  }
  __syncthreads();
  const int d = t >> 2;
  short* dst = Vtsw + ((size_t)bh * 64 + d) * SP_;
  const int sw = (d & 7) << 3;
#pragma unroll
  for (int e = 0; e < 4; ++e) {
    const int jl = (t & 3) * 16 + e * 4;
    const int jg = j0 + jl;
    short4 v;
    v.x = (jg + 0 < SN_) ? T[jl + 0][d] : (short)0;
    v.y = (jg + 1 < SN_) ? T[jl + 1][d] : (short)0;
    v.z = (jg + 2 < SN_) ? T[jl + 2][d] : (short)0;
    v.w = (jg + 3 < SN_) ? T[jl + 3][d] : (short)0;
    *(short4*)&dst[jg ^ sw] = v;
  }
}

// ---------------------------------------------------------------------------
// Kernel 3: MFMA flash attention, swapped-QK in-register softmax, exp2
// domain (Q pre-scaled by log2e/8 -> QK and ctx bias both in log2 units).
// j-masking only on the tail tile (jt==9, replaces pv so pad-poison can't
// leak). Defer-max: skip accO rescale unless row max grew by > 8.
// LDS 37.3 KB -> 4 blocks/CU.
// ---------------------------------------------------------------------------
__launch_bounds__(256)
__global__ void attn_k(const short* __restrict__ Qbf, const short* __restrict__ Ksw,
                       const short* __restrict__ Vtsw, const float* __restrict__ rpe,
                       const unsigned char* __restrict__ rpbu8, float* __restrict__ y) {
  __shared__ short Kt[64 * 64];          // 8 KB
  __shared__ short Vt[64 * 64];          // 8 KB
  __shared__ float ctxs[4][16][53];      // 13.25 KB (per-wave ctx, odd stride)
  __shared__ char urp[8192];             // union: Rp[64][64] short | rpbt[64*80] u8
  short (*Rp)[64] = (short (*)[64])urp;
  unsigned char* rpbt = (unsigned char*)urp;

  const int t = threadIdx.x;
  const int w = t >> 6, lane = t & 63, g = lane >> 4, ln = lane & 15;
  const int qt = blockIdx.x, bh = blockIdx.y;
  const int b = bh / HN_, h = bh - b * HN_;
  const int i0 = qt * 64;
  const size_t rb = (size_t)bh * SN_;
  const short* Kbh = Ksw + (size_t)bh * SP_ * 64;
  const short* Vbh = Vtsw + (size_t)bh * 64 * SP_;

  // staging thread map (shared by K, V, rpb tiles)
  const int sr_ = t >> 2, scu_ = (t & 3) * 16;
  const int irow_s = (i0 + sr_ <= SN_ - 1) ? (i0 + sr_) : (SN_ - 1);

  // prefetch tile jt=0 (overlaps Rp staging + ctx MFMA)
  short8 kr0, kr1, vr0, vr1; int4 rp_;
  {
    const short* ks = Kbh + (size_t)sr_ * 64 + scu_;
    kr0 = *(const short8*)(ks); kr1 = *(const short8*)(ks + 8);
    const short* vs = Vbh + (size_t)sr_ * SP_ + scu_;
    vr0 = *(const short8*)(vs); vr1 = *(const short8*)(vs + 8);
    rp_ = *(const int4*)(rpbu8 + (size_t)irow_s * 640 + scu_);
  }

  // stage rpe^T -> Rp[c][d] (bf16), pad c>=50 with 0
  for (int e = t; e < 64 * 64; e += 256) {
    const int c = e >> 6, d = e & 63;
    Rp[c][d] = (c < NB_) ? f2bf(rpe[d * NB_ + c]) : (short)0;
  }

  // Q fragments (bf16 direct); lane holds Q row i = i0 + 16w + ln
  short8 qf[2];
  {
    int row = i0 + 16 * w + ln; if (row > SN_ - 1) row = SN_ - 1;
    const short* qp = Qbf + (rb + row) * 64;
    qf[0] = *(const short8*)(qp + 8 * g);
    qf[1] = *(const short8*)(qp + 32 + 8 * g);
  }

  __syncthreads();  // Rp ready

  // ctx tile: ctx[i_local=4g+r][c=ct*16+ln] via mfma(qf, rf); keep c<53
  {
    f32x4 accC[4];
#pragma unroll
    for (int ct = 0; ct < 4; ++ct) accC[ct] = (f32x4){0.f, 0.f, 0.f, 0.f};
#pragma unroll
    for (int kc = 0; kc < 2; ++kc) {
#pragma unroll
      for (int ct = 0; ct < 4; ++ct) {
        const short8 rf = *(const short8*)&Rp[ct * 16 + ln][kc * 32 + 8 * g];
        accC[ct] = __builtin_amdgcn_mfma_f32_16x16x32_bf16(qf[kc], rf, accC[ct], 0, 0, 0);
      }
    }
#pragma unroll
    for (int ct = 0; ct < 4; ++ct) {
      const int c = ct * 16 + ln;
      if (c < 53) {
#pragma unroll
        for (int r = 0; r < 4; ++r) ctxs[w][4 * g + r][c] = accC[ct][r];
      }
    }
  }

  float m = -3e38f, l = 0.f;
  f32x4 accO[4];
#pragma unroll
  for (int dt = 0; dt < 4; ++dt) accO[dt] = (f32x4){0.f, 0.f, 0.f, 0.f};

  const int swv = (ln & 7) << 3;
  const float* cbase = &ctxs[w][ln][0];
  const int rpoff = (16 * w + ln) * 80;

  for (int jt = 0; jt < 10; ++jt) {
    const int j0 = jt * 64;
    __syncthreads();  // previous tile's LDS reads (and Rp reads, 1st iter) done
    *(short8*)&Kt[sr_ * 64 + scu_]     = kr0;
    *(short8*)&Kt[sr_ * 64 + scu_ + 8] = kr1;
    *(short8*)&Vt[sr_ * 64 + scu_]     = vr0;
    *(short8*)&Vt[sr_ * 64 + scu_ + 8] = vr1;
    *(int4*)&rpbt[sr_ * 80 + scu_]     = rp_;
    __syncthreads();  // tiles visible

    if (jt < 9) {  // prefetch next tile (latency hides under compute)
      const int jn = j0 + 64;
      const short* ks = Kbh + (size_t)(jn + sr_) * 64 + scu_;
      kr0 = *(const short8*)(ks); kr1 = *(const short8*)(ks + 8);
      const short* vs = Vbh + (size_t)sr_ * SP_ + jn + scu_;
      vr0 = *(const short8*)(vs); vr1 = *(const short8*)(vs + 8);
      rp_ = *(const int4*)(rpbu8 + (size_t)irow_s * 640 + jn + scu_);
    }

    // QK^T swapped: accS[nt][r] = S[i = ln][j = j0 + nt*16 + 4g + r]
    f32x4 accS[4];
#pragma unroll
    for (int nt = 0; nt < 4; ++nt) accS[nt] = (f32x4){0.f, 0.f, 0.f, 0.f};
#pragma unroll
    for (int kc = 0; kc < 2; ++kc) {
      const int cb = (kc * 32 + 8 * g) ^ swv;
#pragma unroll
      for (int nt = 0; nt < 4; ++nt) {
        const short8 kf = *(const short8*)&Kt[(nt * 16 + ln) * 64 + cb];
        accS[nt] = __builtin_amdgcn_mfma_f32_16x16x32_bf16(kf, qf[kc], accS[nt], 0, 0, 0);
      }
    }

    // bias (bucket gather via u8 LDS tile; ctx row ln, odd stride 53)
    float pv[4][4];
#pragma unroll
    for (int nt = 0; nt < 4; ++nt) {
      const uchar4 bk = *(const uchar4*)&rpbt[rpoff + nt * 16 + 4 * g];
      pv[nt][0] = accS[nt][0] + cbase[bk.x];
      pv[nt][1] = accS[nt][1] + cbase[bk.y];
      pv[nt][2] = accS[nt][2] + cbase[bk.z];
      pv[nt][3] = accS[nt][3] + cbase[bk.w];
    }
    if (jt == 9) {  // tail: REPLACE invalid-j entries (poison-proof)
#pragma unroll
      for (int nt = 0; nt < 4; ++nt) {
        const int jb = j0 + nt * 16 + 4 * g;
#pragma unroll
        for (int r = 0; r < 4; ++r)
          if (jb + r >= SN_) pv[nt][r] = -3e38f;
      }
    }

    // online softmax, in-register row (i = ln), exp2 domain
    float mx = fmaxf(fmaxf(pv[0][0], pv[0][1]), fmaxf(pv[0][2], pv[0][3]));
#pragma unroll
    for (int nt = 1; nt < 4; ++nt)
      mx = fmaxf(mx, fmaxf(fmaxf(pv[nt][0], pv[nt][1]), fmaxf(pv[nt][2], pv[nt][3])));
    mx = fmaxf(mx, __shfl_xor(mx, 16));
    mx = fmaxf(mx, __shfl_xor(mx, 32));

    if (__any(mx > m + 8.f)) {  // rescale path (rare after first tiles)
      const float mnew = fmaxf(m, mx);
      const float sc = ex2(m - mnew);
      float scr[4];
#pragma unroll
      for (int r = 0; r < 4; ++r) scr[r] = __shfl(sc, 4 * g + r);
#pragma unroll
      for (int dt = 0; dt < 4; ++dt)
#pragma unroll
        for (int r = 0; r < 4; ++r) accO[dt][r] *= scr[r];
      l *= sc;
      m = mnew;
    }

    float sum = 0.f;
#pragma unroll
    for (int nt = 0; nt < 4; ++nt)
#pragma unroll
      for (int r = 0; r < 4; ++r) {
        const float p = ex2(pv[nt][r] - m);
        pv[nt][r] = p;
        sum += p;
      }
    sum += __shfl_xor(sum, 16);
    sum += __shfl_xor(sum, 32);
    l += sum;

    // pack P to bf16 (slot jj -> j = kc*32 + 16*(jj>>2) + 4g + (jj&3))
    short8 pf[2];
#pragma unroll
    for (int kc = 0; kc < 2; ++kc) {
      union { short8 v; short u[8]; } pk;
#pragma unroll
      for (int r = 0; r < 4; ++r) {
        pk.u[r]     = f2bf(pv[2 * kc][r]);
        pk.u[4 + r] = f2bf(pv[2 * kc + 1][r]);
      }
      pf[kc] = pk.v;
    }

    // PV: accO[dt][r] = O[i=4g+r][d=dt*16+ln]; V^T read with matching slot map
#pragma unroll
    for (int kc = 0; kc < 2; ++kc) {
#pragma unroll
      for (int dt = 0; dt < 4; ++dt) {
        const short* vrow = &Vt[(dt * 16 + ln) * 64];
        union { short8 v; short4 hh[2]; } u;
        u.hh[0] = *(const short4*)&vrow[(kc * 32 + 4 * g) ^ swv];
        u.hh[1] = *(const short4*)&vrow[(kc * 32 + 16 + 4 * g) ^ swv];
        accO[dt] = __builtin_amdgcn_mfma_f32_16x16x32_bf16(pf[kc], u.v, accO[dt], 0, 0, 0);
      }
    }
  }

  // epilogue: y[b, i, h*64 + d] = O / l   (l for row 4g+r via shfl)
  float linv[4];
#pragma unroll
  for (int r = 0; r < 4; ++r) linv[r] = 1.f / __shfl(l, 4 * g + r);
#pragma unroll
  for (int r = 0; r < 4; ++r) {
    const int i = i0 + 16 * w + 4 * g + r;
    if (i >= SN_) continue;
    float* yp = y + ((size_t)b * SN_ + i) * DN_ + h * HD_ + ln;
#pragma unroll
    for (int dt = 0; dt < 4; ++dt) yp[dt * 16] = accO[dt][r] * linv[r];
  }
}

// ---------------------------------------------------------------------------
extern "C" void kernel_launch(void* const* d_in, const int* in_sizes, int n_in,
                              void* d_out, int out_size, void* d_ws, size_t ws_size,
                              hipStream_t stream) {
  const float* x   = (const float*)d_in[0];
  const float* w   = (const float*)d_in[1];
  const float* rpe = (const float*)d_in[2];
  const int*   rpb = (const int*)d_in[3];
  float* y = (float*)d_out;

  short* xb   = (short*)d_ws;                      // 9344*768
  short* wb   = xb + (size_t)MRP_ * DN_;           // 2304*768
  short* Qbf  = wb + (size_t)NQ_ * DN_;            // 110784*64
  short* Ksw  = Qbf + (size_t)BHS_ * HD_;          // 192*640*64
  short* Vbf  = Ksw + (size_t)BN_ * HN_ * SP_ * 64;
  short* Vtsw = Vbf + (size_t)BN_ * HN_ * SP_ * 64;
  unsigned char* rpbu8 = (unsigned char*)(Vtsw + (size_t)BN_ * HN_ * 64 * SP_);  // 577*640

  cvt_k<<<dim3(MRP_ * DN_ / 2048), 256, 0, stream>>>(x, xb, MR_ * DN_, MRP_ * DN_);
  cvt_k<<<dim3(NQ_ * DN_ / 2048), 256, 0, stream>>>(w, wb, NQ_ * DN_, NQ_ * DN_);
  rpb8_k<<<dim3((SN_ * 160 + 255) / 256), 256, 0, stream>>>(rpb, rpbu8);
  qkv_mfma_k<<<dim3(18, 73), 256, 0, stream>>>(xb, wb, Qbf, Ksw, Vbf);
  vtr_k<<<dim3(10, BN_ * HN_), 256, 0, stream>>>(Vbf, Vtsw);
  attn_k<<<dim3(10, BN_ * HN_), 256, 0, stream>>>(Qbf, Ksw, Vtsw, rpe, rpbu8, y);
}